// Round 16
// baseline (247.040 us; speedup 1.0000x reference)
//
#include <hip/hip_runtime.h>
#include <cmath>

// Round 23: retry r21's P-overlay with the launch_bounds bug fixed.
// r21 autopsy: the overlay PASSED correctness and zeroed bank conflicts
// (1.08M -> 0); it died only from __launch_bounds__(256,8) clamping VGPR to
// 32 (< ~36 live-state floor) -> per-chunk spills. Fix: (256,6) — the SAME
// bound the working r14 kernel compiles under (allocator behavior proven,
// ~40-44 VGPR, no clamp). Runtime occupancy is resource-determined: LDS
// 25.6 -> 16KB => 8 blocks/CU (32 waves, +33% TLP) on a latency/sync-bound
// kernel. Cost: +1 barrier/chunk (S2, K-read vs P-write cross-wave hazard).
// Tripwires: WRITE_SIZE must stay ~16MB; VGPR must NOT be 32.
// GEMMs/prep byte-identical to r22 anchor.
// B=4 T=2048 C=1024 H=16 hd=64.

typedef short short8 __attribute__((ext_vector_type(8)));
typedef short short4v __attribute__((ext_vector_type(4)));
typedef float f32x4 __attribute__((ext_vector_type(4)));

__device__ __forceinline__ short f2bf(float f) {
  unsigned u = __builtin_bit_cast(unsigned, f);
  u = (u + 0x7fffu + ((u >> 16) & 1u)) >> 16;   // RNE; inputs are finite
  return (short)u;
}

__device__ __forceinline__ float exp2_fast(float x) {
  float r;
  asm("v_exp_f32 %0, %1" : "=v"(r) : "v"(x));
  return r;
}

__device__ __forceinline__ void gld_lds16(const void* g, void* l) {
  __builtin_amdgcn_global_load_lds(
      (__attribute__((address_space(1))) void*)g,
      (__attribute__((address_space(3))) void*)l,
      16, 0, 0);
}

// raw barrier, opaque to SIInsertWaitcnts (no implicit counter drain)
__device__ __forceinline__ void barx() {
  asm volatile("s_barrier" ::: "memory");
}

// asm ds_read_b128 at byte address + compile-time offset (waitcnt-opaque)
template <int IMM>
__device__ __forceinline__ short8 dsr(int addr) {
  short8 d;
  asm volatile("ds_read_b128 %0, %1 offset:%2"
               : "=v"(d) : "v"(addr), "n"(IMM));
  return d;
}

// counted lgkm wait; sched_barrier stops MFMA motion across it (rule #18)
#define WAITLN(n)                                          \
  asm volatile("s_waitcnt lgkmcnt(" #n ")" ::: "memory");  \
  __builtin_amdgcn_sched_barrier(0);

extern __shared__ short lds[];

// ---------------- cast fp32 -> bf16 bits (4 elems/thread) ----------------
__global__ void cast_bf16_kernel(const float* __restrict__ in,
                                 short* __restrict__ out, int n4) {
  int i = blockIdx.x * blockDim.x + threadIdx.x;
  if (i < n4) {
    const float4 v = ((const float4*)in)[i];
    short4v o;
    o.x = f2bf(v.x); o.y = f2bf(v.y); o.z = f2bf(v.z); o.w = f2bf(v.w);
    ((short4v*)out)[i] = o;
  }
}

// ------------- transpose+cast: fp32 [R][C] -> bf16 [C][R] ----------------
__global__ void transpose_cast_kernel(const float* __restrict__ in,
                                      short* __restrict__ out, int R, int C) {
  __shared__ float tile[32][33];
  int c0 = blockIdx.x * 32, r0 = blockIdx.y * 32;
  int tx = threadIdx.x & 31, tg = threadIdx.x >> 5;
#pragma unroll
  for (int i = 0; i < 4; ++i) {
    int r = tg * 4 + i;
    tile[r][tx] = in[(size_t)(r0 + r) * C + c0 + tx];
  }
  __syncthreads();
#pragma unroll
  for (int i = 0; i < 4; ++i) {
    int c = tg * 4 + i;
    out[(size_t)(c0 + c) * R + r0 + tx] = f2bf(tile[tx][c]);
  }
}

// --------------- GEMM: 128x256 tile, 8-wave, pipelined (r12) -------------
// C = A[M][K] * Bt[N][K]^T + bias. MODE 0: split to q/k (bf16 [bh][t][d],
// q scaled by log2e/8) and vT (bf16 [bh][d][t]), N=3072. MODE 1: fp32
// [M][N] direct. 512 threads = 8 waves (2M x 4N), per-wave C = 64x64.
// LDS: dbuf x (A 128x64 + B 256x64) bf16 = 96KB dynamic, XOR-swizzled via
// pre-swizzled global source.

template <int MODE>
__global__ __launch_bounds__(512, 2) void gemm128_kernel(
    const short* __restrict__ A, const short* __restrict__ Bt,
    const float* __restrict__ bias, float* __restrict__ outf,
    short* __restrict__ oq, short* __restrict__ ok, short* __restrict__ ovt,
    int M, int N, int K) {
  const int NT = K >> 6;  // 16 K-tiles
  const int lane = threadIdx.x & 63, wave = threadIdx.x >> 6;
  const int quad = lane >> 4, l16 = lane & 15;
  const int wm2 = wave >> 2, wn4 = wave & 3;

  // bijective XCD swizzle (grid % 8 == 0); n varies fastest within an XCD
  const int nbn = N >> 8;
  const int swz = (blockIdx.x & 7) * ((int)gridDim.x >> 3) + (blockIdx.x >> 3);
  const int m0 = (swz / nbn) * 128, n0 = (swz % nbn) * 256;

  const int r8 = lane >> 3;
  const int sw8 = ((lane & 7) ^ r8) * 8;
  const short* Ab0 = A + (size_t)(m0 + wave * 8 + r8) * K + sw8;
  const short* Bb0 = Bt + (size_t)(n0 + wave * 8 + r8) * K + sw8;
  short* ldsw = lds + wave * 512;

  auto stage = [&](int t, int mat, int rA, int rB) {
    const short* g = (mat ? Bb0 : Ab0) + t * 64;
    short* d = ldsw + (t & 1) * 24576 + mat * 8192;
    gld_lds16(g + (size_t)rA * K, d + rA * 64);
    gld_lds16(g + (size_t)rB * K, d + rB * 64);
  };

  const int swz0 = ((0 + quad) ^ (l16 & 7)) * 16;  // kh=0
  const int swz1 = ((4 + quad) ^ (l16 & 7)) * 16;  // kh=1
  const int baseA0 = wm2 * 8192 + l16 * 128 + swz0;
  const int baseA1 = wm2 * 8192 + l16 * 128 + swz1;
  const int baseB0 = 16384 + wn4 * 8192 + l16 * 128 + swz0;
  const int baseB1 = 16384 + wn4 * 8192 + l16 * 128 + swz1;

  f32x4 acc[4][4] = {};

  stage(0, 1, 0, 64);
  stage(0, 1, 128, 192);
  stage(0, 0, 0, 64);
  asm volatile("s_waitcnt vmcnt(0)" ::: "memory");
  barx();

#pragma unroll 1
  for (int t = 0; t < NT; ++t) {
    const int vb = (t & 1) * 49152;
    const int aA0 = baseA0 + vb, aA1 = baseA1 + vb;
    const int aB0 = baseB0 + vb, aB1 = baseB1 + vb;
    short8 a0[4], b0[4], a1[4], b1[4];

    b0[0] = dsr<0>(aB0);     b0[1] = dsr<2048>(aB0);
    b0[2] = dsr<4096>(aB0);  b0[3] = dsr<6144>(aB0);
    a0[0] = dsr<0>(aA0);     a0[1] = dsr<2048>(aA0);
    a0[2] = dsr<4096>(aA0);  a0[3] = dsr<6144>(aA0);
    if (t + 1 < NT) {
      stage(t + 1, 1, 0, 64);
      stage(t + 1, 1, 128, 192);
      stage(t + 1, 0, 0, 64);
    }
    b1[0] = dsr<0>(aB1);     b1[1] = dsr<2048>(aB1);
    b1[2] = dsr<4096>(aB1);  b1[3] = dsr<6144>(aB1);
    a1[0] = dsr<0>(aA1);     a1[1] = dsr<2048>(aA1);
    a1[2] = dsr<4096>(aA1);  a1[3] = dsr<6144>(aA1);

    WAITLN(8)  // kh0's 8 reads retired (DS in-order); kh1 still in flight
    __builtin_amdgcn_s_setprio(1);
#pragma unroll
    for (int i_ = 0; i_ < 4; ++i_)
#pragma unroll
      for (int n_ = 0; n_ < 4; ++n_)
        acc[i_][n_] = __builtin_amdgcn_mfma_f32_16x16x32_bf16(
            a0[i_], b0[n_], acc[i_][n_], 0, 0, 0);
    __builtin_amdgcn_s_setprio(0);

    WAITLN(0)  // kh1 ready
    __builtin_amdgcn_s_setprio(1);
#pragma unroll
    for (int i_ = 0; i_ < 4; ++i_)
#pragma unroll
      for (int n_ = 0; n_ < 4; ++n_)
        acc[i_][n_] = __builtin_amdgcn_mfma_f32_16x16x32_bf16(
            a1[i_], b1[n_], acc[i_][n_], 0, 0, 0);
    __builtin_amdgcn_s_setprio(0);

    if (t + 1 < NT)
      asm volatile("s_waitcnt vmcnt(0)" ::: "memory");
    barx();
  }

  // ------------------------------ epilogue -------------------------------
  float bv[4];
#pragma unroll
  for (int n_ = 0; n_ < 4; ++n_) bv[n_] = bias[n0 + wn4 * 64 + n_ * 16 + l16];

  if (MODE == 1) {
    // direct fp32 [M][N] store
#pragma unroll
    for (int mt = 0; mt < 4; ++mt)
#pragma unroll
      for (int n_ = 0; n_ < 4; ++n_) {
        const int n = n0 + wn4 * 64 + n_ * 16 + l16;
#pragma unroll
        for (int r = 0; r < 4; ++r) {
          const int m = m0 + wm2 * 64 + mt * 16 + quad * 4 + r;
          outf[(size_t)m * N + n] = acc[mt][n_][r] + bv[n_];
        }
      }
    return;
  }

  const int sec = n0 >> 10;                 // 0=q 1=k 2=v
  const int h0 = (n0 & 1023) >> 6;
  const float scale = (sec == 0) ? 0.18033688f : 1.0f;  // log2e/8 into q
  const int b_ = m0 >> 11, t0 = m0 & 2047;

  __syncthreads();  // all waves past K-loop; LDS free for repack
  if (sec < 2) {
    // Cs[128][264] bf16 (67.6KB); rows = 128 t, cols = 256 (4 heads x 64 d)
    short* dst = (sec == 0) ? oq : ok;
#pragma unroll
    for (int mt = 0; mt < 4; ++mt)
#pragma unroll
      for (int n_ = 0; n_ < 4; ++n_) {
        const int col = wn4 * 64 + n_ * 16 + l16;
#pragma unroll
        for (int r = 0; r < 4; ++r)
          lds[(wm2 * 64 + mt * 16 + quad * 4 + r) * 264 + col] =
              f2bf((acc[mt][n_][r] + bv[n_]) * scale);
      }
    __syncthreads();
    // wave w: head w&3, row-half w>>2; each iter = 8 t-rows x 64 d = 1KB
    const int hl = wave & 3, rg = wave >> 2;
    const short* sp = &lds[(rg * 64 + r8) * 264 + hl * 64 + (lane & 7) * 8];
    short* gp = dst +
        ((size_t)(b_ * 16 + h0 + hl) * 2048 + t0 + rg * 64 + r8) * 64 +
        (lane & 7) * 8;
#pragma unroll
    for (int i = 0; i < 8; ++i)
      *(short8*)(gp + (size_t)i * 512) = *(const short8*)(sp + i * 8 * 264);
  } else {
    // v: transposed repack; Cs[256 cols][136] bf16 (69.6KB)
#pragma unroll
    for (int mt = 0; mt < 4; ++mt)
#pragma unroll
      for (int n_ = 0; n_ < 4; ++n_) {
        const int col = wn4 * 64 + n_ * 16 + l16;
#pragma unroll
        for (int r = 0; r < 4; ++r)
          lds[col * 136 + wm2 * 64 + mt * 16 + quad * 4 + r] =
              f2bf(acc[mt][n_][r] + bv[n_]);
      }
    __syncthreads();
    // wave w covers cols [w*32,+32): 16 lanes per col, 8 rows each
    const int cw = wave * 32 + (lane >> 4);
#pragma unroll
    for (int i = 0; i < 8; ++i) {
      const int c = cw + i * 4;
      const int bh = b_ * 16 + h0 + (c >> 6), d = c & 63;
      *(short8*)(ovt + ((size_t)bh * 64 + d) * 2048 + t0 + (lane & 15) * 8) =
          *(const short8*)&lds[c * 136 + (lane & 15) * 8];
    }
  }
}

// --------------------------- flash attention -----------------------------
// r14 body + P-overlay (r21 idea, launch_bounds fixed): P written into Ks
// (own wave's 16-row region, granule swizzle (kcol/8)^(row&7)) after a
// post-QK^T barrier; Ps buffer removed. LDS = Ks 8KB + Vs 8KB = 16KB ->
// runtime 8 blocks/CU (32 waves). launch_bounds (256,6) = same compiler
// budget as the proven r14 kernel (~40-44 VGPR, no clamp/spill).
// 3 barriers/chunk: S1 post-stage, S2 post-QK^T (cross-wave K-read vs
// P-write), S3 post-PV (cross-wave V-read + P-read vs next stage).
__global__ __launch_bounds__(256, 6) void attn_kernel(
    const short* __restrict__ q, const short* __restrict__ k,
    const short* __restrict__ vt, short* __restrict__ y) {
  __shared__ short Ks[64 * 64];   // K chunk; overlaid by P after QK^T
  __shared__ short Vs[64 * 64];
  const int lane = threadIdx.x & 63, wave = threadIdx.x >> 6;
  const int quad = lane >> 4, l16 = lane & 15;
  const int g = blockIdx.x;
  const int bh = g & 63;
  const int j = 31 - (g >> 6);  // big blocks dispatched first
  const int b_ = bh >> 4, h = bh & 15;
  const int q0 = j * 64 + wave * 16;

  const short* qbh = q + (size_t)bh * 2048 * 64;
  const short* kbh = k + (size_t)bh * 2048 * 64;
  const short* vbh = vt + (size_t)bh * 64 * 2048;

  const short8 qf0 = *(const short8*)&qbh[(q0 + l16) * 64 + quad * 8];
  const short8 qf1 = *(const short8*)&qbh[(q0 + l16) * 64 + 32 + quad * 8];

  short8 ones;
#pragma unroll
  for (int i = 0; i < 8; ++i) ones[i] = (short)0x3F80;  // bf16 1.0

  f32x4 O[4] = {};
  f32x4 lacc = {};

  const int srow = lane >> 3;
  const int scol = ((lane & 7) ^ srow) * 8;
  const int r0s = wave * 16;
  // P overlay addressing (shorts): value (qrow=pr, kcol) stored at row
  // r0s+pr, granule (kcol/8)^(pr&7), elem kcol%8. Reads (pf0/pf1) recover
  // granule quad^(l16&7) / (quad+4)^(l16&7) at row r0s+l16 — conflict-free
  // b128, same swizzle family as the K-read path (r21: measured 0 conflicts).
  const int pcolg = l16 >> 3, pel = l16 & 7;

#pragma unroll 1
  for (int c = 0; c <= j; ++c) {
    const int kt0 = c * 64;
    gld_lds16(kbh + (size_t)(kt0 + r0s + srow) * 64 + scol, &Ks[r0s * 64]);
    gld_lds16(kbh + (size_t)(kt0 + r0s + 8 + srow) * 64 + scol, &Ks[(r0s + 8) * 64]);
    gld_lds16(vbh + (size_t)(r0s + srow) * 2048 + kt0 + scol, &Vs[r0s * 64]);
    gld_lds16(vbh + (size_t)(r0s + 8 + srow) * 2048 + kt0 + scol, &Vs[(r0s + 8) * 64]);
    __syncthreads();  // S1: stage visible

    const int sw = l16 & 7;
    f32x4 sc4[4];
#pragma unroll
    for (int cf = 0; cf < 4; ++cf) {
      const int row = cf * 16 + l16;
      const short8 kfa = *(const short8*)&Ks[row * 64 + ((quad ^ sw) * 8)];
      const short8 kfb = *(const short8*)&Ks[row * 64 + (((quad + 4) ^ sw) * 8)];
      f32x4 z = {};
      z = __builtin_amdgcn_mfma_f32_16x16x32_bf16(qf0, kfa, z, 0, 0, 0);
      z = __builtin_amdgcn_mfma_f32_16x16x32_bf16(qf1, kfb, z, 0, 0, 0);
      sc4[cf] = z;
    }
    __syncthreads();  // S2: all waves' K reads done -> Ks reusable as P

    if (c == j) {
#pragma unroll
      for (int cf = 0; cf < 4; ++cf) {
        const int col = kt0 + cf * 16 + l16;
#pragma unroll
        for (int r = 0; r < 4; ++r) {
          const int rowg = q0 + quad * 4 + r;
          float e = exp2_fast(sc4[cf][r]);
          e = (col > rowg) ? 0.f : e;
          const int pr = quad * 4 + r;
          Ks[(r0s + pr) * 64 + (((cf * 2 + pcolg) ^ (pr & 7)) * 8) + pel] =
              f2bf(e);
        }
      }
    } else {
#pragma unroll
      for (int cf = 0; cf < 4; ++cf)
#pragma unroll
        for (int r = 0; r < 4; ++r) {
          const int pr = quad * 4 + r;
          Ks[(r0s + pr) * 64 + (((cf * 2 + pcolg) ^ (pr & 7)) * 8) + pel] =
              f2bf(exp2_fast(sc4[cf][r]));
        }
    }
    asm volatile("s_waitcnt lgkmcnt(0)" ::: "memory");
    const short8 pf0 = *(const short8*)&Ks[(r0s + l16) * 64 + ((quad ^ sw) * 8)];
    const short8 pf1 =
        *(const short8*)&Ks[(r0s + l16) * 64 + (((quad + 4) ^ sw) * 8)];

    lacc = __builtin_amdgcn_mfma_f32_16x16x32_bf16(pf0, ones, lacc, 0, 0, 0);
    lacc = __builtin_amdgcn_mfma_f32_16x16x32_bf16(pf1, ones, lacc, 0, 0, 0);

#pragma unroll
    for (int dt = 0; dt < 4; ++dt) {
      const int d = dt * 16 + l16;
      const short8 vf0 = *(const short8*)&Vs[d * 64 + ((quad ^ sw) * 8)];
      const short8 vf1 = *(const short8*)&Vs[d * 64 + (((quad + 4) ^ sw) * 8)];
      O[dt] = __builtin_amdgcn_mfma_f32_16x16x32_bf16(pf0, vf0, O[dt], 0, 0, 0);
      O[dt] = __builtin_amdgcn_mfma_f32_16x16x32_bf16(pf1, vf1, O[dt], 0, 0, 0);
    }
    __syncthreads();  // S3: V reads (+ own P reads) done -> next stage safe
  }

  float inv[4];
#pragma unroll
  for (int r = 0; r < 4; ++r) inv[r] = 1.0f / lacc[r];
#pragma unroll
  for (int dt = 0; dt < 4; ++dt) {
    const int d = dt * 16 + l16;
#pragma unroll
    for (int r = 0; r < 4; ++r) {
      const int t_ = q0 + quad * 4 + r;
      y[((size_t)b_ * 2048 + t_) * 1024 + h * 64 + d] = f2bf(O[dt][r] * inv[r]);
    }
  }
}

// -------------------------------------------------------------------------
extern "C" void kernel_launch(void* const* d_in, const int* in_sizes, int n_in,
                              void* d_out, int out_size, void* d_ws, size_t ws_size,
                              hipStream_t stream) {
  const float* x      = (const float*)d_in[0];
  const float* w_attn = (const float*)d_in[1];
  const float* b_attn = (const float*)d_in[2];
  const float* w_proj = (const float*)d_in[3];
  const float* b_proj = (const float*)d_in[4];
  float* out = (float*)d_out;

  short* xb  = (short*)d_ws;                    // [8192][1024]
  short* wTa = xb + (size_t)8192 * 1024;        // [3072][1024]
  short* wTp = wTa + (size_t)3072 * 1024;       // [1024][1024]
  short* qb  = wTp + (size_t)1024 * 1024;       // [64][2048][64]
  short* kb  = qb + (size_t)64 * 2048 * 64;     // [64][2048][64]
  short* vtb = kb + (size_t)64 * 2048 * 64;     // [64][64][2048]
  short* yb  = vtb + (size_t)64 * 2048 * 64;    // [8192][1024]

  static int lds_attr_done = 0;
  if (!lds_attr_done) {
    (void)hipFuncSetAttribute(
        reinterpret_cast<const void*>(&gemm128_kernel<0>),
        hipFuncAttributeMaxDynamicSharedMemorySize, 98304);
    (void)hipFuncSetAttribute(
        reinterpret_cast<const void*>(&gemm128_kernel<1>),
        hipFuncAttributeMaxDynamicSharedMemorySize, 98304);
    lds_attr_done = 1;
  }

  cast_bf16_kernel<<<8192, 256, 0, stream>>>(x, xb, 8192 * 1024 / 4);
  transpose_cast_kernel<<<dim3(96, 32), 256, 0, stream>>>(w_attn, wTa, 1024, 3072);
  transpose_cast_kernel<<<dim3(32, 32), 256, 0, stream>>>(w_proj, wTp, 1024, 1024);

  gemm128_kernel<0><<<768, 512, 98304, stream>>>(
      xb, wTa, b_attn, nullptr, qb, kb, vtb, 8192, 3072, 1024);

  attn_kernel<<<2048, 256, 0, stream>>>(qb, kb, vtb, yb);

  gemm128_kernel<1><<<256, 512, 98304, stream>>>(
      yb, wTp, b_proj, out, nullptr, nullptr, nullptr, 8192, 1024, 1024);
}

// Round 17
// 235.862 us; speedup vs baseline: 1.0474x; 1.0474x over previous
//
#include <hip/hip_runtime.h>
#include <cmath>

// Round 24 (FINAL): restore the anchor (235.9-238.5us across 4 reproductions).
// r23 closed the P-overlay arc: with launch_bounds fixed (VGPR 40, conflicts
// 0) it STILL lost — occupancy never rose (55.6%, same as 6-block baseline),
// a light spill appeared (WRITE 16->34.6MB), and the 3rd barrier serialized.
// attn experiments 0/6 (r13/r15/r16/r17/r21/r23), each a distinct failure
// mechanism -> r14 attn is a robust local optimum; escape = co-designed
// swapped-QK^T in-register-softmax rewrite (multi-round, out of scope).
// Session deliverable: 259.9 -> ~236us (-9.2%) via r12 pipelined dual-window
// 128x256 GEMM + r13 MODE-split fused q/k/vT epilogues + r12 attn.
// B=4 T=2048 C=1024 H=16 hd=64.

typedef short short8 __attribute__((ext_vector_type(8)));
typedef short short4v __attribute__((ext_vector_type(4)));
typedef float f32x4 __attribute__((ext_vector_type(4)));

__device__ __forceinline__ short f2bf(float f) {
  unsigned u = __builtin_bit_cast(unsigned, f);
  u = (u + 0x7fffu + ((u >> 16) & 1u)) >> 16;   // RNE; inputs are finite
  return (short)u;
}

__device__ __forceinline__ float exp2_fast(float x) {
  float r;
  asm("v_exp_f32 %0, %1" : "=v"(r) : "v"(x));
  return r;
}

__device__ __forceinline__ void gld_lds16(const void* g, void* l) {
  __builtin_amdgcn_global_load_lds(
      (__attribute__((address_space(1))) void*)g,
      (__attribute__((address_space(3))) void*)l,
      16, 0, 0);
}

// raw barrier, opaque to SIInsertWaitcnts (no implicit counter drain)
__device__ __forceinline__ void barx() {
  asm volatile("s_barrier" ::: "memory");
}

// asm ds_read_b128 at byte address + compile-time offset (waitcnt-opaque)
template <int IMM>
__device__ __forceinline__ short8 dsr(int addr) {
  short8 d;
  asm volatile("ds_read_b128 %0, %1 offset:%2"
               : "=v"(d) : "v"(addr), "n"(IMM));
  return d;
}

// counted lgkm wait; sched_barrier stops MFMA motion across it (rule #18)
#define WAITLN(n)                                          \
  asm volatile("s_waitcnt lgkmcnt(" #n ")" ::: "memory");  \
  __builtin_amdgcn_sched_barrier(0);

extern __shared__ short lds[];

// ---------------- cast fp32 -> bf16 bits (4 elems/thread) ----------------
__global__ void cast_bf16_kernel(const float* __restrict__ in,
                                 short* __restrict__ out, int n4) {
  int i = blockIdx.x * blockDim.x + threadIdx.x;
  if (i < n4) {
    const float4 v = ((const float4*)in)[i];
    short4v o;
    o.x = f2bf(v.x); o.y = f2bf(v.y); o.z = f2bf(v.z); o.w = f2bf(v.w);
    ((short4v*)out)[i] = o;
  }
}

// ------------- transpose+cast: fp32 [R][C] -> bf16 [C][R] ----------------
__global__ void transpose_cast_kernel(const float* __restrict__ in,
                                      short* __restrict__ out, int R, int C) {
  __shared__ float tile[32][33];
  int c0 = blockIdx.x * 32, r0 = blockIdx.y * 32;
  int tx = threadIdx.x & 31, tg = threadIdx.x >> 5;
#pragma unroll
  for (int i = 0; i < 4; ++i) {
    int r = tg * 4 + i;
    tile[r][tx] = in[(size_t)(r0 + r) * C + c0 + tx];
  }
  __syncthreads();
#pragma unroll
  for (int i = 0; i < 4; ++i) {
    int c = tg * 4 + i;
    out[(size_t)(c0 + c) * R + r0 + tx] = f2bf(tile[tx][c]);
  }
}

// --------------- GEMM: 128x256 tile, 8-wave, pipelined (r12) -------------
// C = A[M][K] * Bt[N][K]^T + bias. MODE 0: split to q/k (bf16 [bh][t][d],
// q scaled by log2e/8) and vT (bf16 [bh][d][t]), N=3072. MODE 1: fp32
// [M][N] direct. 512 threads = 8 waves (2M x 4N), per-wave C = 64x64.
// LDS: dbuf x (A 128x64 + B 256x64) bf16 = 96KB dynamic, XOR-swizzled via
// pre-swizzled global source.

template <int MODE>
__global__ __launch_bounds__(512, 2) void gemm128_kernel(
    const short* __restrict__ A, const short* __restrict__ Bt,
    const float* __restrict__ bias, float* __restrict__ outf,
    short* __restrict__ oq, short* __restrict__ ok, short* __restrict__ ovt,
    int M, int N, int K) {
  const int NT = K >> 6;  // 16 K-tiles
  const int lane = threadIdx.x & 63, wave = threadIdx.x >> 6;
  const int quad = lane >> 4, l16 = lane & 15;
  const int wm2 = wave >> 2, wn4 = wave & 3;

  // bijective XCD swizzle (grid % 8 == 0); n varies fastest within an XCD
  const int nbn = N >> 8;
  const int swz = (blockIdx.x & 7) * ((int)gridDim.x >> 3) + (blockIdx.x >> 3);
  const int m0 = (swz / nbn) * 128, n0 = (swz % nbn) * 256;

  const int r8 = lane >> 3;
  const int sw8 = ((lane & 7) ^ r8) * 8;
  const short* Ab0 = A + (size_t)(m0 + wave * 8 + r8) * K + sw8;
  const short* Bb0 = Bt + (size_t)(n0 + wave * 8 + r8) * K + sw8;
  short* ldsw = lds + wave * 512;

  auto stage = [&](int t, int mat, int rA, int rB) {
    const short* g = (mat ? Bb0 : Ab0) + t * 64;
    short* d = ldsw + (t & 1) * 24576 + mat * 8192;
    gld_lds16(g + (size_t)rA * K, d + rA * 64);
    gld_lds16(g + (size_t)rB * K, d + rB * 64);
  };

  const int swz0 = ((0 + quad) ^ (l16 & 7)) * 16;  // kh=0
  const int swz1 = ((4 + quad) ^ (l16 & 7)) * 16;  // kh=1
  const int baseA0 = wm2 * 8192 + l16 * 128 + swz0;
  const int baseA1 = wm2 * 8192 + l16 * 128 + swz1;
  const int baseB0 = 16384 + wn4 * 8192 + l16 * 128 + swz0;
  const int baseB1 = 16384 + wn4 * 8192 + l16 * 128 + swz1;

  f32x4 acc[4][4] = {};

  stage(0, 1, 0, 64);
  stage(0, 1, 128, 192);
  stage(0, 0, 0, 64);
  asm volatile("s_waitcnt vmcnt(0)" ::: "memory");
  barx();

#pragma unroll 1
  for (int t = 0; t < NT; ++t) {
    const int vb = (t & 1) * 49152;
    const int aA0 = baseA0 + vb, aA1 = baseA1 + vb;
    const int aB0 = baseB0 + vb, aB1 = baseB1 + vb;
    short8 a0[4], b0[4], a1[4], b1[4];

    b0[0] = dsr<0>(aB0);     b0[1] = dsr<2048>(aB0);
    b0[2] = dsr<4096>(aB0);  b0[3] = dsr<6144>(aB0);
    a0[0] = dsr<0>(aA0);     a0[1] = dsr<2048>(aA0);
    a0[2] = dsr<4096>(aA0);  a0[3] = dsr<6144>(aA0);
    if (t + 1 < NT) {
      stage(t + 1, 1, 0, 64);
      stage(t + 1, 1, 128, 192);
      stage(t + 1, 0, 0, 64);
    }
    b1[0] = dsr<0>(aB1);     b1[1] = dsr<2048>(aB1);
    b1[2] = dsr<4096>(aB1);  b1[3] = dsr<6144>(aB1);
    a1[0] = dsr<0>(aA1);     a1[1] = dsr<2048>(aA1);
    a1[2] = dsr<4096>(aA1);  a1[3] = dsr<6144>(aA1);

    WAITLN(8)  // kh0's 8 reads retired (DS in-order); kh1 still in flight
    __builtin_amdgcn_s_setprio(1);
#pragma unroll
    for (int i_ = 0; i_ < 4; ++i_)
#pragma unroll
      for (int n_ = 0; n_ < 4; ++n_)
        acc[i_][n_] = __builtin_amdgcn_mfma_f32_16x16x32_bf16(
            a0[i_], b0[n_], acc[i_][n_], 0, 0, 0);
    __builtin_amdgcn_s_setprio(0);

    WAITLN(0)  // kh1 ready
    __builtin_amdgcn_s_setprio(1);
#pragma unroll
    for (int i_ = 0; i_ < 4; ++i_)
#pragma unroll
      for (int n_ = 0; n_ < 4; ++n_)
        acc[i_][n_] = __builtin_amdgcn_mfma_f32_16x16x32_bf16(
            a1[i_], b1[n_], acc[i_][n_], 0, 0, 0);
    __builtin_amdgcn_s_setprio(0);

    if (t + 1 < NT)
      asm volatile("s_waitcnt vmcnt(0)" ::: "memory");
    barx();
  }

  // ------------------------------ epilogue -------------------------------
  float bv[4];
#pragma unroll
  for (int n_ = 0; n_ < 4; ++n_) bv[n_] = bias[n0 + wn4 * 64 + n_ * 16 + l16];

  if (MODE == 1) {
    // direct fp32 [M][N] store
#pragma unroll
    for (int mt = 0; mt < 4; ++mt)
#pragma unroll
      for (int n_ = 0; n_ < 4; ++n_) {
        const int n = n0 + wn4 * 64 + n_ * 16 + l16;
#pragma unroll
        for (int r = 0; r < 4; ++r) {
          const int m = m0 + wm2 * 64 + mt * 16 + quad * 4 + r;
          outf[(size_t)m * N + n] = acc[mt][n_][r] + bv[n_];
        }
      }
    return;
  }

  const int sec = n0 >> 10;                 // 0=q 1=k 2=v
  const int h0 = (n0 & 1023) >> 6;
  const float scale = (sec == 0) ? 0.18033688f : 1.0f;  // log2e/8 into q
  const int b_ = m0 >> 11, t0 = m0 & 2047;

  __syncthreads();  // all waves past K-loop; LDS free for repack
  if (sec < 2) {
    // Cs[128][264] bf16 (67.6KB); rows = 128 t, cols = 256 (4 heads x 64 d)
    short* dst = (sec == 0) ? oq : ok;
#pragma unroll
    for (int mt = 0; mt < 4; ++mt)
#pragma unroll
      for (int n_ = 0; n_ < 4; ++n_) {
        const int col = wn4 * 64 + n_ * 16 + l16;
#pragma unroll
        for (int r = 0; r < 4; ++r)
          lds[(wm2 * 64 + mt * 16 + quad * 4 + r) * 264 + col] =
              f2bf((acc[mt][n_][r] + bv[n_]) * scale);
      }
    __syncthreads();
    // wave w: head w&3, row-half w>>2; each iter = 8 t-rows x 64 d = 1KB
    const int hl = wave & 3, rg = wave >> 2;
    const short* sp = &lds[(rg * 64 + r8) * 264 + hl * 64 + (lane & 7) * 8];
    short* gp = dst +
        ((size_t)(b_ * 16 + h0 + hl) * 2048 + t0 + rg * 64 + r8) * 64 +
        (lane & 7) * 8;
#pragma unroll
    for (int i = 0; i < 8; ++i)
      *(short8*)(gp + (size_t)i * 512) = *(const short8*)(sp + i * 8 * 264);
  } else {
    // v: transposed repack; Cs[256 cols][136] bf16 (69.6KB)
#pragma unroll
    for (int mt = 0; mt < 4; ++mt)
#pragma unroll
      for (int n_ = 0; n_ < 4; ++n_) {
        const int col = wn4 * 64 + n_ * 16 + l16;
#pragma unroll
        for (int r = 0; r < 4; ++r)
          lds[col * 136 + wm2 * 64 + mt * 16 + quad * 4 + r] =
              f2bf(acc[mt][n_][r] + bv[n_]);
      }
    __syncthreads();
    // wave w covers cols [w*32,+32): 16 lanes per col, 8 rows each
    const int cw = wave * 32 + (lane >> 4);
#pragma unroll
    for (int i = 0; i < 8; ++i) {
      const int c = cw + i * 4;
      const int bh = b_ * 16 + h0 + (c >> 6), d = c & 63;
      *(short8*)(ovt + ((size_t)bh * 64 + d) * 2048 + t0 + (lane & 15) * 8) =
          *(const short8*)&lds[c * 136 + (lane & 15) * 8];
    }
  }
}

// --------------------------- flash attention -----------------------------
// (round-12/14 known-good version, FROZEN: Ks/Vs staged via gld_lds,
// 2 barriers/chunk, 25.6KB static LDS -> 6 blocks/CU)
__global__ __launch_bounds__(256, 6) void attn_kernel(
    const short* __restrict__ q, const short* __restrict__ k,
    const short* __restrict__ vt, short* __restrict__ y) {
  __shared__ short Ks[64 * 64];
  __shared__ short Vs[64 * 64];
  __shared__ short Ps[4][16 * 72];
  const int lane = threadIdx.x & 63, wave = threadIdx.x >> 6;
  const int quad = lane >> 4, l16 = lane & 15;
  const int g = blockIdx.x;
  const int bh = g & 63;
  const int j = 31 - (g >> 6);  // big blocks dispatched first
  const int b_ = bh >> 4, h = bh & 15;
  const int q0 = j * 64 + wave * 16;

  const short* qbh = q + (size_t)bh * 2048 * 64;
  const short* kbh = k + (size_t)bh * 2048 * 64;
  const short* vbh = vt + (size_t)bh * 64 * 2048;
  short* Pw = Ps[wave];

  const short8 qf0 = *(const short8*)&qbh[(q0 + l16) * 64 + quad * 8];
  const short8 qf1 = *(const short8*)&qbh[(q0 + l16) * 64 + 32 + quad * 8];

  short8 ones;
#pragma unroll
  for (int i = 0; i < 8; ++i) ones[i] = (short)0x3F80;  // bf16 1.0

  f32x4 O[4] = {};
  f32x4 lacc = {};

  const int srow = lane >> 3;
  const int scol = ((lane & 7) ^ srow) * 8;
  const int r0s = wave * 16;

#pragma unroll 1
  for (int c = 0; c <= j; ++c) {
    const int kt0 = c * 64;
    gld_lds16(kbh + (size_t)(kt0 + r0s + srow) * 64 + scol, &Ks[r0s * 64]);
    gld_lds16(kbh + (size_t)(kt0 + r0s + 8 + srow) * 64 + scol, &Ks[(r0s + 8) * 64]);
    gld_lds16(vbh + (size_t)(r0s + srow) * 2048 + kt0 + scol, &Vs[r0s * 64]);
    gld_lds16(vbh + (size_t)(r0s + 8 + srow) * 2048 + kt0 + scol, &Vs[(r0s + 8) * 64]);
    __syncthreads();

    const int sw = l16 & 7;
    f32x4 sc4[4];
#pragma unroll
    for (int cf = 0; cf < 4; ++cf) {
      const int row = cf * 16 + l16;
      const short8 kfa = *(const short8*)&Ks[row * 64 + ((quad ^ sw) * 8)];
      const short8 kfb = *(const short8*)&Ks[row * 64 + (((quad + 4) ^ sw) * 8)];
      f32x4 z = {};
      z = __builtin_amdgcn_mfma_f32_16x16x32_bf16(qf0, kfa, z, 0, 0, 0);
      z = __builtin_amdgcn_mfma_f32_16x16x32_bf16(qf1, kfb, z, 0, 0, 0);
      sc4[cf] = z;
    }

    if (c == j) {
#pragma unroll
      for (int cf = 0; cf < 4; ++cf) {
        const int col = kt0 + cf * 16 + l16;
#pragma unroll
        for (int r = 0; r < 4; ++r) {
          const int rowg = q0 + quad * 4 + r;
          float e = exp2_fast(sc4[cf][r]);
          e = (col > rowg) ? 0.f : e;
          Pw[(quad * 4 + r) * 72 + cf * 16 + l16] = f2bf(e);
        }
      }
    } else {
#pragma unroll
      for (int cf = 0; cf < 4; ++cf)
#pragma unroll
        for (int r = 0; r < 4; ++r)
          Pw[(quad * 4 + r) * 72 + cf * 16 + l16] = f2bf(exp2_fast(sc4[cf][r]));
    }
    asm volatile("s_waitcnt lgkmcnt(0)" ::: "memory");
    const short8 pf0 = *(const short8*)&Pw[l16 * 72 + quad * 8];
    const short8 pf1 = *(const short8*)&Pw[l16 * 72 + 32 + quad * 8];

    lacc = __builtin_amdgcn_mfma_f32_16x16x32_bf16(pf0, ones, lacc, 0, 0, 0);
    lacc = __builtin_amdgcn_mfma_f32_16x16x32_bf16(pf1, ones, lacc, 0, 0, 0);

#pragma unroll
    for (int dt = 0; dt < 4; ++dt) {
      const int d = dt * 16 + l16;
      const short8 vf0 = *(const short8*)&Vs[d * 64 + ((quad ^ sw) * 8)];
      const short8 vf1 = *(const short8*)&Vs[d * 64 + (((quad + 4) ^ sw) * 8)];
      O[dt] = __builtin_amdgcn_mfma_f32_16x16x32_bf16(pf0, vf0, O[dt], 0, 0, 0);
      O[dt] = __builtin_amdgcn_mfma_f32_16x16x32_bf16(pf1, vf1, O[dt], 0, 0, 0);
    }
    __syncthreads();
  }

  float inv[4];
#pragma unroll
  for (int r = 0; r < 4; ++r) inv[r] = 1.0f / lacc[r];
#pragma unroll
  for (int dt = 0; dt < 4; ++dt) {
    const int d = dt * 16 + l16;
#pragma unroll
    for (int r = 0; r < 4; ++r) {
      const int t_ = q0 + quad * 4 + r;
      y[((size_t)b_ * 2048 + t_) * 1024 + h * 64 + d] = f2bf(O[dt][r] * inv[r]);
    }
  }
}

// -------------------------------------------------------------------------
extern "C" void kernel_launch(void* const* d_in, const int* in_sizes, int n_in,
                              void* d_out, int out_size, void* d_ws, size_t ws_size,
                              hipStream_t stream) {
  const float* x      = (const float*)d_in[0];
  const float* w_attn = (const float*)d_in[1];
  const float* b_attn = (const float*)d_in[2];
  const float* w_proj = (const float*)d_in[3];
  const float* b_proj = (const float*)d_in[4];
  float* out = (float*)d_out;

  short* xb  = (short*)d_ws;                    // [8192][1024]
  short* wTa = xb + (size_t)8192 * 1024;        // [3072][1024]
  short* wTp = wTa + (size_t)3072 * 1024;       // [1024][1024]
  short* qb  = wTp + (size_t)1024 * 1024;       // [64][2048][64]
  short* kb  = qb + (size_t)64 * 2048 * 64;     // [64][2048][64]
  short* vtb = kb + (size_t)64 * 2048 * 64;     // [64][64][2048]
  short* yb  = vtb + (size_t)64 * 2048 * 64;    // [8192][1024]

  static int lds_attr_done = 0;
  if (!lds_attr_done) {
    (void)hipFuncSetAttribute(
        reinterpret_cast<const void*>(&gemm128_kernel<0>),
        hipFuncAttributeMaxDynamicSharedMemorySize, 98304);
    (void)hipFuncSetAttribute(
        reinterpret_cast<const void*>(&gemm128_kernel<1>),
        hipFuncAttributeMaxDynamicSharedMemorySize, 98304);
    lds_attr_done = 1;
  }

  cast_bf16_kernel<<<8192, 256, 0, stream>>>(x, xb, 8192 * 1024 / 4);
  transpose_cast_kernel<<<dim3(96, 32), 256, 0, stream>>>(w_attn, wTa, 1024, 3072);
  transpose_cast_kernel<<<dim3(32, 32), 256, 0, stream>>>(w_proj, wTp, 1024, 1024);

  gemm128_kernel<0><<<768, 512, 98304, stream>>>(
      xb, wTa, b_attn, nullptr, qb, kb, vtb, 8192, 3072, 1024);

  attn_kernel<<<2048, 256, 0, stream>>>(qb, kb, vtb, yb);

  gemm128_kernel<1><<<256, 512, 98304, stream>>>(
      yb, wTp, b_proj, out, nullptr, nullptr, nullptr, 8192, 1024, 1024);
}